// Round 6
// baseline (665.936 us; speedup 1.0000x reference)
//
#include <hip/hip_runtime.h>

// SimplePoseGNN on MI355X — round 6.
// fp32 in/out; internal bf16 + fp32 accumulation; bf16 MFMA GEMMs.
// Structure: conv1 does TWO fused GEMMs per block (h1 then H1W = (h1*n_out)@W2 via
// LDS tile) + R3 pose residual. conv2 has NO GEMM: edge-parallel gather of H1W rows
// (contiguous per-block edge range, packed src|lrow<<18) into fp32 LDS tile via
// ds_add_f32, then per-channel bn/relu + pose dot. Graph mean via binary search.

#define NN 139264
#define EE 278528
#define GG 8192
#define NBLK 544    // NN/256
#define EBLK 1088   // EE/256
#define TSTR 260    // fp32 tile row stride (64x260 f32, padded vs 256 for bank spread)

typedef float f32x4 __attribute__((ext_vector_type(4)));
typedef __bf16 bf16x8 __attribute__((ext_vector_type(8)));
typedef unsigned short u16x8 __attribute__((ext_vector_type(8)));

__device__ __forceinline__ float bf2f(unsigned short u) {
    unsigned int i = ((unsigned int)u) << 16;
    float f;
    __builtin_memcpy(&f, &i, 4);
    return f;
}
__device__ __forceinline__ unsigned short f2bf(float f) {
    unsigned int i;
    __builtin_memcpy(&i, &f, 4);
    i += 0x7fffu + ((i >> 16) & 1u);   // round-to-nearest-even
    return (unsigned short)(i >> 16);
}

// ---------------- workspace layout (bytes) ----------------
#define OFF_DEG_OUT ((size_t)0)
#define OFF_DEG_IN  ((size_t)557056)
#define ZERO_BYTES  ((size_t)1114112)
#define OFF_NOUT    ((size_t)1114112)
#define OFF_NIN     ((size_t)1671168)
#define OFF_ROWPTR  ((size_t)2228224)
#define OFF_CURSOR  ((size_t)2788352)
#define OFF_CSRS    ((size_t)3345408)
#define OFF_BSUM    ((size_t)4459520)
#define OFF_WT1     ((size_t)4463616)
#define OFF_WT2     ((size_t)4594688)
#define OFF_WTA     ((size_t)4725760)
#define OFF_WTB     ((size_t)4856832)
#define OFF_WTCLS   ((size_t)4987904)
#define OFF_BNS     ((size_t)5020672)
#define OFF_BNH     ((size_t)5026816)
#define OFF_T       ((size_t)5032960)
#define OFF_R3      ((size_t)6704128)
#define OFF_H1W     ((size_t)8375296)
// total ~79.7 MB

// ---------------- graph preprocessing ----------------

__global__ void k_deg(const int* __restrict__ src, const int* __restrict__ dst,
                      int* __restrict__ deg_out, int* __restrict__ deg_in) {
    int e = blockIdx.x * 256 + threadIdx.x;
    if (e < EE) {
        atomicAdd(&deg_out[src[e]], 1);
        atomicAdd(&deg_in[dst[e]], 1);
    }
}

__global__ void k_scan1(const int* __restrict__ deg, int* __restrict__ part, int* __restrict__ bsum) {
    __shared__ int sh[256];
    int t = threadIdx.x, gid = blockIdx.x * 256 + t;
    int v = deg[gid];
    sh[t] = v;
    __syncthreads();
#pragma unroll
    for (int off = 1; off < 256; off <<= 1) {
        int a = (t >= off) ? sh[t - off] : 0;
        __syncthreads();
        sh[t] += a;
        __syncthreads();
    }
    part[gid] = sh[t] - v;
    if (t == 255) bsum[blockIdx.x] = sh[t];
}

__global__ void k_scan2(int* __restrict__ bsum) {
    __shared__ int sh[1024];
    int t = threadIdx.x;
    int v = (t < NBLK) ? bsum[t] : 0;
    sh[t] = v;
    __syncthreads();
#pragma unroll
    for (int off = 1; off < 1024; off <<= 1) {
        int a = (t >= off) ? sh[t - off] : 0;
        __syncthreads();
        sh[t] += a;
        __syncthreads();
    }
    if (t < NBLK) bsum[t] = sh[t] - v;
}

// scan finalize + cursor copy + norm factors
__global__ void k_scan3(int* __restrict__ rp, const int* __restrict__ bsum, int* __restrict__ cursor,
                        const int* __restrict__ dego, const int* __restrict__ degi,
                        float* __restrict__ n_out, float* __restrict__ n_in) {
    int t = threadIdx.x, gid = blockIdx.x * 256 + t;
    int v = rp[gid] + bsum[blockIdx.x];
    rp[gid] = v;
    cursor[gid] = v;
    if (gid == 0) rp[NN] = EE;
    n_out[gid] = rsqrtf((float)max(dego[gid], 1));
    n_in[gid]  = rsqrtf((float)max(degi[gid], 1));
}

// fill packed CSR: pk[pos] = src | (local_row << 18)
__global__ void k_fill(const int* __restrict__ src, const int* __restrict__ dst,
                       int* __restrict__ cursor, int* __restrict__ csr) {
    int e = blockIdx.x * 256 + threadIdx.x;
    int d = dst[e];
    int pos = atomicAdd(&cursor[d], 1);
    csr[pos] = src[e] | ((d & 63) << 18);
}

// per-row conv1 stats: T[r] = n_in[r] * { Σ sc*nf0, Σ sc*nf1, Σ sc },  sc = n_out[src]
__global__ void k_rowstats(const int* __restrict__ rp, const int* __restrict__ csr,
                           const float* __restrict__ n_out, const float* __restrict__ n_in,
                           const float* __restrict__ nf, float* __restrict__ T) {
    int r = blockIdx.x * 256 + threadIdx.x;
    int e0 = rp[r], e1 = rp[r + 1];
    float S0 = 0.f, S1 = 0.f, S2 = 0.f;
    for (int e = e0; e < e1; e++) {
        int s = csr[e] & 0x3FFFF;
        float sc = n_out[s];
        S0 = fmaf(sc, nf[2 * s], S0);
        S1 = fmaf(sc, nf[2 * s + 1], S1);
        S2 += sc;
    }
    float ni = n_in[r];
    T[3 * r]     = S0 * ni;
    T[3 * r + 1] = S1 * ni;
    T[3 * r + 2] = S2 * ni;
}

// ---------------- weight / bn prep ----------------
__global__ void k_prep(const float* __restrict__ w0, const float* __restrict__ w1,
                       const float* __restrict__ w2, const float* __restrict__ w3,
                       unsigned short* __restrict__ t0, unsigned short* __restrict__ t1,
                       unsigned short* __restrict__ t2, unsigned short* __restrict__ t3,
                       const float* __restrict__ wcls, unsigned short* __restrict__ tcls,
                       const float* __restrict__ g, const float* __restrict__ b,
                       const float* __restrict__ m, const float* __restrict__ v,
                       float* __restrict__ bns, float* __restrict__ bnh) {
    int t = blockIdx.x * 256 + threadIdx.x;
    int y = blockIdx.y;
    if (y < 4) {
        int k = t >> 8, n = t & 255;
        const float* w = (y == 0) ? w0 : (y == 1) ? w1 : (y == 2) ? w2 : w3;
        unsigned short* o = (y == 0) ? t0 : (y == 1) ? t1 : (y == 2) ? t2 : t3;
        o[n * 256 + k] = f2bf(w[t]);
    } else if (y == 4) {
        if (t < 16384) {
            int n = t >> 8, k = t & 255;
            tcls[t] = (n < 60) ? f2bf(wcls[k * 60 + n]) : (unsigned short)0;
        }
    } else {
        if (t < 1536) {
            float inv = rsqrtf(v[t] + 1e-5f);
            float s = g[t] * inv;
            bns[t] = s;
            bnh[t] = b[t] - m[t] * s;
        }
    }
}

// ---------------- conv1: GEMM1 (A from T,Wemb) -> y -> LDS -> GEMM2 -> H1W; R3 ----------------
// y = emb_resid + relu(bn1(relu(bn0( A @ W1 + b1 ))));  R3 = y @ Wout;
// H1W = (y * n_out[row]) @ W2   (bias b2 / bn2 applied later in conv2)
__launch_bounds__(256)
__global__ void k_conv1(const float* __restrict__ T, const float* __restrict__ nf,
                        const float* __restrict__ Wemb, const float* __restrict__ bemb,
                        const unsigned short* __restrict__ Wt1, const float* __restrict__ bias,
                        const unsigned short* __restrict__ Wt2,
                        const float* __restrict__ bns0, const float* __restrict__ bnh0,
                        const float* __restrict__ Wout, const float* __restrict__ n_out,
                        unsigned short* __restrict__ h1w, float* __restrict__ R3) {
    __shared__ unsigned char tileY[64 * 512];   // swizzled bf16 (y * n_out)
    __shared__ float pl[4][64][3];
    int lane = threadIdx.x & 63, wave = threadIdx.x >> 6;
    int wrow = blockIdx.x * 64;
    int rsel = lane & 15, kq = lane >> 4;
    float t0[4], t1[4], t2[4];
#pragma unroll
    for (int mt = 0; mt < 4; mt++) {
        int r = wrow + mt * 16 + rsel;
        t0[mt] = T[3 * r]; t1[mt] = T[3 * r + 1]; t2[mt] = T[3 * r + 2];
    }
    f32x4 acc[4][4];
    f32x4 zero = {0.f, 0.f, 0.f, 0.f};
#pragma unroll
    for (int i = 0; i < 4; i++)
#pragma unroll
        for (int j = 0; j < 4; j++) acc[i][j] = zero;

#pragma unroll
    for (int kt = 0; kt < 8; kt++) {
        int k0 = kt * 32 + kq * 8;
        float w0s[8], w1s[8], bes[8];
        *(float4*)w0s = *(const float4*)(Wemb + k0);       *(float4*)(w0s + 4) = *(const float4*)(Wemb + k0 + 4);
        *(float4*)w1s = *(const float4*)(Wemb + 256 + k0); *(float4*)(w1s + 4) = *(const float4*)(Wemb + 256 + k0 + 4);
        *(float4*)bes = *(const float4*)(bemb + k0);       *(float4*)(bes + 4) = *(const float4*)(bemb + k0 + 4);
        bf16x8 afr[4];
#pragma unroll
        for (int mt = 0; mt < 4; mt++) {
            u16x8 au;
#pragma unroll
            for (int j = 0; j < 8; j++)
                au[j] = f2bf(fmaf(t0[mt], w0s[j], fmaf(t1[mt], w1s[j], t2[mt] * bes[j])));
            afr[mt] = __builtin_bit_cast(bf16x8, au);
        }
        bf16x8 bfr[4];
#pragma unroll
        for (int nt = 0; nt < 4; nt++) {
            u16x8 bu = *(const u16x8*)(Wt1 + (size_t)(wave * 64 + nt * 16 + rsel) * 256 + k0);
            bfr[nt] = __builtin_bit_cast(bf16x8, bu);
        }
#pragma unroll
        for (int mt = 0; mt < 4; mt++)
#pragma unroll
            for (int nt = 0; nt < 4; nt++)
                acc[mt][nt] = __builtin_amdgcn_mfma_f32_16x16x32_bf16(afr[mt], bfr[nt], acc[mt][nt], 0, 0, 0);
    }

    // epilogue A: bn chain + emb residual; y*n_out -> LDS tile; pose partials -> pl
#pragma unroll
    for (int mt = 0; mt < 4; mt++) {
        float f0[4], f1[4], no[4];
        float p0[4] = {0.f, 0.f, 0.f, 0.f};
        float p1[4] = {0.f, 0.f, 0.f, 0.f};
        float p2[4] = {0.f, 0.f, 0.f, 0.f};
#pragma unroll
        for (int r = 0; r < 4; r++) {
            int row = wrow + mt * 16 + kq * 4 + r;
            float2 p = *(const float2*)(nf + 2 * (size_t)row);
            f0[r] = p.x; f1[r] = p.y;
            no[r] = n_out[row];
        }
#pragma unroll
        for (int nt = 0; nt < 4; nt++) {
            int col = wave * 64 + nt * 16 + rsel;
            float bc = bias[col];
            float s0 = bns0[col], h0 = bnh0[col];
            float s1 = bns0[256 + col], h1v = bnh0[256 + col];
            float we0 = Wemb[col], we1 = Wemb[256 + col], be = bemb[col];
            const float* wp = Wout + (size_t)col * 3;
            float w30 = wp[0], w31 = wp[1], w32 = wp[2];
#pragma unroll
            for (int r = 0; r < 4; r++) {
                int lrow = mt * 16 + kq * 4 + r;
                float y = acc[mt][nt][r] + bc;
                y = fmaxf(fmaf(y, s0, h0), 0.f);
                y = fmaxf(fmaf(y, s1, h1v), 0.f);
                y += fmaf(f0[r], we0, fmaf(f1[r], we1, be));
                *(unsigned short*)(tileY + lrow * 512 + ((col * 2) ^ ((lrow & 7) << 4))) = f2bf(y * no[r]);
                p0[r] = fmaf(y, w30, p0[r]);
                p1[r] = fmaf(y, w31, p1[r]);
                p2[r] = fmaf(y, w32, p2[r]);
            }
        }
#pragma unroll
        for (int m = 1; m < 16; m <<= 1) {
#pragma unroll
            for (int r = 0; r < 4; r++) {
                p0[r] += __shfl_xor(p0[r], m);
                p1[r] += __shfl_xor(p1[r], m);
                p2[r] += __shfl_xor(p2[r], m);
            }
        }
        if (rsel == 0) {
#pragma unroll
            for (int r = 0; r < 4; r++) {
                int lrow = mt * 16 + kq * 4 + r;
                pl[wave][lrow][0] = p0[r];
                pl[wave][lrow][1] = p1[r];
                pl[wave][lrow][2] = p2[r];
            }
        }
    }
    __syncthreads();
    int tid = threadIdx.x;
    if (tid < 192) {
        int lrow = tid / 3, c = tid % 3;
        R3[(size_t)(wrow + lrow) * 3 + c] =
            pl[0][lrow][c] + pl[1][lrow][c] + pl[2][lrow][c] + pl[3][lrow][c];
    }

    // phase B: H1W = tileY @ W2
    f32x4 acc2[4][4];
#pragma unroll
    for (int i = 0; i < 4; i++)
#pragma unroll
        for (int j = 0; j < 4; j++) acc2[i][j] = zero;
#pragma unroll
    for (int kt = 0; kt < 8; kt++) {
        int cb = kt * 64 + kq * 16;
        int k0 = kt * 32 + kq * 8;
        bf16x8 afr[4];
#pragma unroll
        for (int mt = 0; mt < 4; mt++) {
            int ar = mt * 16 + rsel;
            u16x8 au = *(const u16x8*)(tileY + ar * 512 + (cb ^ ((ar & 7) << 4)));
            afr[mt] = __builtin_bit_cast(bf16x8, au);
        }
        bf16x8 bfr[4];
#pragma unroll
        for (int nt = 0; nt < 4; nt++) {
            u16x8 bu = *(const u16x8*)(Wt2 + (size_t)(wave * 64 + nt * 16 + rsel) * 256 + k0);
            bfr[nt] = __builtin_bit_cast(bf16x8, bu);
        }
#pragma unroll
        for (int mt = 0; mt < 4; mt++)
#pragma unroll
            for (int nt = 0; nt < 4; nt++)
                acc2[mt][nt] = __builtin_amdgcn_mfma_f32_16x16x32_bf16(afr[mt], bfr[nt], acc2[mt][nt], 0, 0, 0);
    }
#pragma unroll
    for (int mt = 0; mt < 4; mt++)
#pragma unroll
        for (int nt = 0; nt < 4; nt++) {
            int col = wave * 64 + nt * 16 + rsel;
#pragma unroll
            for (int r = 0; r < 4; r++) {
                int row = wrow + mt * 16 + kq * 4 + r;
                h1w[(size_t)row * 256 + col] = f2bf(acc2[mt][nt][r]);
            }
        }
}

// ---------------- conv2: edge-parallel gather of H1W + bn/relu + pose ----------------
// tile[lrow] += H1W[src] over block's contiguous edge range; then per channel:
// y = relu(bn3(relu(bn2( tile*n_in + b2 ))));  h3d = y@Wout + R3 + bout
__launch_bounds__(256)
__global__ void k_conv2(const int* __restrict__ rp, const int* __restrict__ pk,
                        const float* __restrict__ n_in, const unsigned short* __restrict__ h1w,
                        const float* __restrict__ bc2,
                        const float* __restrict__ bns0, const float* __restrict__ bnh0,
                        const float* __restrict__ Wout, const float* __restrict__ bout,
                        const float* __restrict__ R3, float* __restrict__ h3d) {
    __shared__ float tile[64 * TSTR];
    __shared__ float pl[4][64][3];
    int lane = threadIdx.x & 63, wave = threadIdx.x >> 6;
    int wrow = blockIdx.x * 64;
    int rsel = lane & 15, kq = lane >> 4;

    // zero tile
    for (int i = threadIdx.x; i < 64 * TSTR / 4; i += 256)
        ((f32x4*)tile)[i] = (f32x4){0.f, 0.f, 0.f, 0.f};
    __syncthreads();

    // edge-parallel accumulate (4 contiguous chunks, one per wave)
    int eb0 = rp[wrow], eb1 = rp[wrow + 64];
    int len = eb1 - eb0;
    int ews = eb0 + ((len * wave) >> 2);
    int ewe = eb0 + ((len * (wave + 1)) >> 2);
    int e = ews;
    for (; e + 4 <= ewe; e += 4) {
        int p0 = pk[e], p1 = pk[e + 1], p2 = pk[e + 2], p3 = pk[e + 3];
        const unsigned short* b0 = h1w + ((size_t)(p0 & 0x3FFFF) << 8);
        const unsigned short* b1 = h1w + ((size_t)(p1 & 0x3FFFF) << 8);
        const unsigned short* b2 = h1w + ((size_t)(p2 & 0x3FFFF) << 8);
        const unsigned short* b3 = h1w + ((size_t)(p3 & 0x3FFFF) << 8);
        unsigned short q0[4], q1[4], q2[4], q3[4];
#pragma unroll
        for (int j = 0; j < 4; j++) {
            q0[j] = b0[lane + 64 * j];
            q1[j] = b1[lane + 64 * j];
            q2[j] = b2[lane + 64 * j];
            q3[j] = b3[lane + 64 * j];
        }
        float* r0 = tile + (p0 >> 18) * TSTR;
        float* r1 = tile + (p1 >> 18) * TSTR;
        float* r2 = tile + (p2 >> 18) * TSTR;
        float* r3 = tile + (p3 >> 18) * TSTR;
#pragma unroll
        for (int j = 0; j < 4; j++) {
            unsafeAtomicAdd(r0 + lane + 64 * j, bf2f(q0[j]));
            unsafeAtomicAdd(r1 + lane + 64 * j, bf2f(q1[j]));
            unsafeAtomicAdd(r2 + lane + 64 * j, bf2f(q2[j]));
            unsafeAtomicAdd(r3 + lane + 64 * j, bf2f(q3[j]));
        }
    }
    for (; e < ewe; e++) {
        int p = pk[e];
        const unsigned short* b = h1w + ((size_t)(p & 0x3FFFF) << 8);
        float* rr = tile + (p >> 18) * TSTR;
#pragma unroll
        for (int j = 0; j < 4; j++)
            unsafeAtomicAdd(rr + lane + 64 * j, bf2f(b[lane + 64 * j]));
    }
    __syncthreads();

    // epilogue: per-channel bn/relu + pose partials (wave owns 64 cols)
#pragma unroll
    for (int mt = 0; mt < 4; mt++) {
        float ni[4];
        float p0[4] = {0.f, 0.f, 0.f, 0.f};
        float p1[4] = {0.f, 0.f, 0.f, 0.f};
        float p2[4] = {0.f, 0.f, 0.f, 0.f};
#pragma unroll
        for (int r = 0; r < 4; r++)
            ni[r] = n_in[wrow + mt * 16 + kq * 4 + r];
#pragma unroll
        for (int nt = 0; nt < 4; nt++) {
            int col = wave * 64 + nt * 16 + rsel;
            float bc = bc2[col];
            float s0 = bns0[col], h0 = bnh0[col];
            float s1 = bns0[256 + col], h1v = bnh0[256 + col];
            const float* wp = Wout + (size_t)col * 3;
            float w30 = wp[0], w31 = wp[1], w32 = wp[2];
#pragma unroll
            for (int r = 0; r < 4; r++) {
                int lrow = mt * 16 + kq * 4 + r;
                float y = fmaf(tile[lrow * TSTR + col], ni[r], bc);
                y = fmaxf(fmaf(y, s0, h0), 0.f);
                y = fmaxf(fmaf(y, s1, h1v), 0.f);
                p0[r] = fmaf(y, w30, p0[r]);
                p1[r] = fmaf(y, w31, p1[r]);
                p2[r] = fmaf(y, w32, p2[r]);
            }
        }
#pragma unroll
        for (int m = 1; m < 16; m <<= 1) {
#pragma unroll
            for (int r = 0; r < 4; r++) {
                p0[r] += __shfl_xor(p0[r], m);
                p1[r] += __shfl_xor(p1[r], m);
                p2[r] += __shfl_xor(p2[r], m);
            }
        }
        if (rsel == 0) {
#pragma unroll
            for (int r = 0; r < 4; r++) {
                int lrow = mt * 16 + kq * 4 + r;
                pl[wave][lrow][0] = p0[r];
                pl[wave][lrow][1] = p1[r];
                pl[wave][lrow][2] = p2[r];
            }
        }
    }
    __syncthreads();
    int tid = threadIdx.x;
    if (tid < 192) {
        int lrow = tid / 3, c = tid % 3;
        int row = wrow + lrow;
        h3d[(size_t)row * 3 + c] =
            pl[0][lrow][c] + pl[1][lrow][c] + pl[2][lrow][c] + pl[3][lrow][c]
            + R3[(size_t)row * 3 + c] + bout[c];
    }
}

// ---------------- fused classification head (gmean via binary search) ----------------
__launch_bounds__(256)
__global__ void k_head(const int* __restrict__ n2g, const float* __restrict__ h3d,
                       const float* __restrict__ Wci, const float* __restrict__ bci,
                       const unsigned short* __restrict__ wta, const float* __restrict__ ba,
                       const unsigned short* __restrict__ wtb, const float* __restrict__ bb,
                       const unsigned short* __restrict__ wtcls, const float* __restrict__ bcls,
                       const float* __restrict__ bns, const float* __restrict__ bnh,
                       float* __restrict__ label) {
    __shared__ unsigned char smem[65536];
    int lane = threadIdx.x & 63, wave = threadIdx.x >> 6;
    unsigned char* tileA = smem + wave * 8192;
    unsigned char* tileB = smem + 32768 + wave * 8192;
    int wrow = blockIdx.x * 64 + wave * 16;
    int rsel = lane & 15, kq = lane >> 4;
    int g = wrow + rsel;              // graph id for this lane

    // graph node range via binary search on sorted n2g
    int lo = 0, hi = NN;
    while (lo < hi) { int mid = (lo + hi) >> 1; if (n2g[mid] < g) lo = mid + 1; else hi = mid; }
    int s = lo;
    hi = NN;
    while (lo < hi) { int mid = (lo + hi) >> 1; if (n2g[mid] < g + 1) lo = mid + 1; else hi = mid; }
    int e = lo;
    float m0 = 0.f, m1 = 0.f, m2 = 0.f;
    for (int j = s; j < e; j++) {
        m0 += h3d[(size_t)j * 3];
        m1 += h3d[(size_t)j * 3 + 1];
        m2 += h3d[(size_t)j * 3 + 2];
    }
    float inv = 1.f / fmaxf((float)(e - s), 1.f);
    m0 *= inv; m1 *= inv; m2 *= inv;

    f32x4 zero = {0.f, 0.f, 0.f, 0.f};
    f32x4 acc[16];
#pragma unroll
    for (int i = 0; i < 16; i++) acc[i] = zero;

    // stage 1: z1 = relu(bn4(z0 @ Wa + ba)), z0 built on the fly
#pragma unroll
    for (int kt = 0; kt < 8; kt++) {
        int k0 = kt * 32 + kq * 8;
        u16x8 au;
#pragma unroll
        for (int j = 0; j < 8; j++)
            au[j] = f2bf(fmaf(m0, Wci[k0 + j], fmaf(m1, Wci[256 + k0 + j],
                         fmaf(m2, Wci[512 + k0 + j], bci[k0 + j]))));
        bf16x8 af = __builtin_bit_cast(bf16x8, au);
#pragma unroll
        for (int nt = 0; nt < 16; nt++) {
            u16x8 bu = *(const u16x8*)(wta + (size_t)(nt * 16 + rsel) * 256 + k0);
            acc[nt] = __builtin_amdgcn_mfma_f32_16x16x32_bf16(af, __builtin_bit_cast(bf16x8, bu), acc[nt], 0, 0, 0);
        }
    }
#pragma unroll
    for (int nt = 0; nt < 16; nt++) {
        int col = nt * 16 + rsel;
        float bcv = ba[col];
        float sc = bns[4 * 256 + col], h = bnh[4 * 256 + col];
#pragma unroll
        for (int r = 0; r < 4; r++) {
            float y = fmaxf(fmaf(acc[nt][r] + bcv, sc, h), 0.f);
            int rr = kq * 4 + r;
            *(unsigned short*)(tileA + rr * 512 + ((col * 2) ^ ((rr & 7) << 4))) = f2bf(y);
        }
    }

    // stage 2: z2 = relu(bn5(z1 @ Wb + bb))
#pragma unroll
    for (int i = 0; i < 16; i++) acc[i] = zero;
#pragma unroll
    for (int kt = 0; kt < 8; kt++) {
        int cb = kt * 64 + kq * 16;
        u16x8 au = *(const u16x8*)(tileA + rsel * 512 + (cb ^ ((rsel & 7) << 4)));
        bf16x8 af = __builtin_bit_cast(bf16x8, au);
        int k0 = kt * 32 + kq * 8;
#pragma unroll
        for (int nt = 0; nt < 16; nt++) {
            u16x8 bu = *(const u16x8*)(wtb + (size_t)(nt * 16 + rsel) * 256 + k0);
            acc[nt] = __builtin_amdgcn_mfma_f32_16x16x32_bf16(af, __builtin_bit_cast(bf16x8, bu), acc[nt], 0, 0, 0);
        }
    }
#pragma unroll
    for (int nt = 0; nt < 16; nt++) {
        int col = nt * 16 + rsel;
        float bcv = bb[col];
        float sc = bns[5 * 256 + col], h = bnh[5 * 256 + col];
#pragma unroll
        for (int r = 0; r < 4; r++) {
            float y = fmaxf(fmaf(acc[nt][r] + bcv, sc, h), 0.f);
            int rr = kq * 4 + r;
            *(unsigned short*)(tileB + rr * 512 + ((col * 2) ^ ((rr & 7) << 4))) = f2bf(y);
        }
    }

    // stage 3: label = z2 @ Wcls + bcls (60 cols)
    f32x4 acc3[4];
#pragma unroll
    for (int i = 0; i < 4; i++) acc3[i] = zero;
#pragma unroll
    for (int kt = 0; kt < 8; kt++) {
        int cb = kt * 64 + kq * 16;
        u16x8 au = *(const u16x8*)(tileB + rsel * 512 + (cb ^ ((rsel & 7) << 4)));
        bf16x8 af = __builtin_bit_cast(bf16x8, au);
        int k0 = kt * 32 + kq * 8;
#pragma unroll
        for (int nt = 0; nt < 4; nt++) {
            u16x8 bu = *(const u16x8*)(wtcls + (size_t)(nt * 16 + rsel) * 256 + k0);
            acc3[nt] = __builtin_amdgcn_mfma_f32_16x16x32_bf16(af, __builtin_bit_cast(bf16x8, bu), acc3[nt], 0, 0, 0);
        }
    }
    int rowb = wrow + kq * 4;
#pragma unroll
    for (int nt = 0; nt < 4; nt++) {
        int col = nt * 16 + rsel;
        if (col < 60) {
            float bcv = bcls[col];
#pragma unroll
            for (int r = 0; r < 4; r++)
                label[(size_t)(rowb + r) * 60 + col] = acc3[nt][r] + bcv;
        }
    }
}

// ---------------- launch ----------------
extern "C" void kernel_launch(void* const* d_in, const int* in_sizes, int n_in,
                              void* d_out, int out_size, void* d_ws, size_t ws_size,
                              hipStream_t stream) {
    const float* nf   = (const float*)d_in[0];
    const int* src    = (const int*)d_in[1];
    const int* dst    = (const int*)d_in[2];
    const int* n2g    = (const int*)d_in[3];
    const float* Wemb = (const float*)d_in[4];
    const float* bemb = (const float*)d_in[5];
    const float* Wc1  = (const float*)d_in[6];
    const float* bc1  = (const float*)d_in[7];
    const float* Wc2  = (const float*)d_in[8];
    const float* bc2  = (const float*)d_in[9];
    const float* bng  = (const float*)d_in[10];
    const float* bnb  = (const float*)d_in[11];
    const float* bnm  = (const float*)d_in[12];
    const float* bnv  = (const float*)d_in[13];
    const float* Wout = (const float*)d_in[14];
    const float* bout = (const float*)d_in[15];
    const float* Wci  = (const float*)d_in[16];
    const float* bci  = (const float*)d_in[17];
    const float* Wb3a = (const float*)d_in[18];
    const float* bb3a = (const float*)d_in[19];
    const float* Wb3b = (const float*)d_in[20];
    const float* bb3b = (const float*)d_in[21];
    const float* Wcls = (const float*)d_in[22];
    const float* bcls = (const float*)d_in[23];

    char* ws = (char*)d_ws;
    int* deg_out = (int*)(ws + OFF_DEG_OUT);
    int* deg_in  = (int*)(ws + OFF_DEG_IN);
    float* n_out = (float*)(ws + OFF_NOUT);
    float* n_inp = (float*)(ws + OFF_NIN);
    int* row_ptr = (int*)(ws + OFF_ROWPTR);
    int* cursor  = (int*)(ws + OFF_CURSOR);
    int* csr_pk  = (int*)(ws + OFF_CSRS);
    int* bsum    = (int*)(ws + OFF_BSUM);
    unsigned short* wt1   = (unsigned short*)(ws + OFF_WT1);
    unsigned short* wt2   = (unsigned short*)(ws + OFF_WT2);
    unsigned short* wta   = (unsigned short*)(ws + OFF_WTA);
    unsigned short* wtb   = (unsigned short*)(ws + OFF_WTB);
    unsigned short* wtcls = (unsigned short*)(ws + OFF_WTCLS);
    float* bns = (float*)(ws + OFF_BNS);
    float* bnh = (float*)(ws + OFF_BNH);
    float* T   = (float*)(ws + OFF_T);
    float* R3  = (float*)(ws + OFF_R3);
    unsigned short* h1w = (unsigned short*)(ws + OFF_H1W);

    float* h3d_out   = (float*)d_out;
    float* label_out = (float*)d_out + (size_t)NN * 3;

    hipMemsetAsync(ws, 0, ZERO_BYTES, stream);   // deg_out, deg_in

    k_deg<<<EBLK, 256, 0, stream>>>(src, dst, deg_out, deg_in);
    k_scan1<<<NBLK, 256, 0, stream>>>(deg_in, row_ptr, bsum);
    k_scan2<<<1, 1024, 0, stream>>>(bsum);
    k_scan3<<<NBLK, 256, 0, stream>>>(row_ptr, bsum, cursor, deg_out, deg_in, n_out, n_inp);
    k_fill<<<EBLK, 256, 0, stream>>>(src, dst, cursor, csr_pk);
    k_prep<<<dim3(256, 6), 256, 0, stream>>>(Wc1, Wc2, Wb3a, Wb3b, wt1, wt2, wta, wtb,
                                             Wcls, wtcls, bng, bnb, bnm, bnv, bns, bnh);
    k_rowstats<<<NBLK, 256, 0, stream>>>(row_ptr, csr_pk, n_out, n_inp, nf, T);

    k_conv1<<<NN / 64, 256, 0, stream>>>(T, nf, Wemb, bemb, wt1, bc1, wt2,
                                         bns, bnh, Wout, n_out, h1w, R3);
    k_conv2<<<NN / 64, 256, 0, stream>>>(row_ptr, csr_pk, n_inp, h1w, bc2,
                                         bns + 512, bnh + 512, Wout, bout, R3, h3d_out);
    k_head<<<GG / 64, 256, 0, stream>>>(n2g, h3d_out, Wci, bci, wta, bb3a, wtb, bb3b,
                                        wtcls, bcls, bns, bnh, label_out);
}

// Round 7
// 300.768 us; speedup vs baseline: 2.2141x; 2.2141x over previous
//
#include <hip/hip_runtime.h>

// SimplePoseGNN on MI355X — round 7.
// fp32 in/out; internal bf16 + fp32 accumulation; bf16 MFMA GEMMs.
// conv1: two fused GEMMs (h1, then H1W=(h1*n_out)@W2 via LDS tile) + R3 pose resid.
// conv2 (k_gconv): NO GEMM, NO atomics, NO LDS — one row per half-wave, register
// fp32 accumulation of H1W[src] rows, bn/relu chain + pose dot + shfl reduce.
// Graph mean via binary search on sorted node2graph. Fully fused classification head.

#define NN 139264
#define EE 278528
#define GG 8192
#define NBLK 544    // NN/256
#define EBLK 1088   // EE/256

typedef float f32x4 __attribute__((ext_vector_type(4)));
typedef __bf16 bf16x8 __attribute__((ext_vector_type(8)));
typedef unsigned short u16x8 __attribute__((ext_vector_type(8)));

__device__ __forceinline__ float bf2f(unsigned short u) {
    unsigned int i = ((unsigned int)u) << 16;
    float f;
    __builtin_memcpy(&f, &i, 4);
    return f;
}
__device__ __forceinline__ unsigned short f2bf(float f) {
    unsigned int i;
    __builtin_memcpy(&i, &f, 4);
    i += 0x7fffu + ((i >> 16) & 1u);   // round-to-nearest-even
    return (unsigned short)(i >> 16);
}

// ---------------- workspace layout (bytes) ----------------
#define OFF_DEG_OUT ((size_t)0)
#define OFF_DEG_IN  ((size_t)557056)
#define ZERO_BYTES  ((size_t)1114112)
#define OFF_NOUT    ((size_t)1114112)
#define OFF_NIN     ((size_t)1671168)
#define OFF_ROWPTR  ((size_t)2228224)
#define OFF_CURSOR  ((size_t)2788352)
#define OFF_CSRS    ((size_t)3345408)
#define OFF_BSUM    ((size_t)4459520)
#define OFF_WT1     ((size_t)4463616)
#define OFF_WT2     ((size_t)4594688)
#define OFF_WTA     ((size_t)4725760)
#define OFF_WTB     ((size_t)4856832)
#define OFF_WTCLS   ((size_t)4987904)
#define OFF_BNS     ((size_t)5020672)
#define OFF_BNH     ((size_t)5026816)
#define OFF_T       ((size_t)5032960)
#define OFF_R3      ((size_t)6704128)
#define OFF_H1W     ((size_t)8375296)
// total ~79.7 MB

// ---------------- graph preprocessing ----------------

__global__ void k_deg(const int* __restrict__ src, const int* __restrict__ dst,
                      int* __restrict__ deg_out, int* __restrict__ deg_in) {
    int e = blockIdx.x * 256 + threadIdx.x;
    if (e < EE) {
        atomicAdd(&deg_out[src[e]], 1);
        atomicAdd(&deg_in[dst[e]], 1);
    }
}

__global__ void k_scan1(const int* __restrict__ deg, int* __restrict__ part, int* __restrict__ bsum) {
    __shared__ int sh[256];
    int t = threadIdx.x, gid = blockIdx.x * 256 + t;
    int v = deg[gid];
    sh[t] = v;
    __syncthreads();
#pragma unroll
    for (int off = 1; off < 256; off <<= 1) {
        int a = (t >= off) ? sh[t - off] : 0;
        __syncthreads();
        sh[t] += a;
        __syncthreads();
    }
    part[gid] = sh[t] - v;
    if (t == 255) bsum[blockIdx.x] = sh[t];
}

__global__ void k_scan2(int* __restrict__ bsum) {
    __shared__ int sh[1024];
    int t = threadIdx.x;
    int v = (t < NBLK) ? bsum[t] : 0;
    sh[t] = v;
    __syncthreads();
#pragma unroll
    for (int off = 1; off < 1024; off <<= 1) {
        int a = (t >= off) ? sh[t - off] : 0;
        __syncthreads();
        sh[t] += a;
        __syncthreads();
    }
    if (t < NBLK) bsum[t] = sh[t] - v;
}

// scan finalize + cursor copy + norm factors
__global__ void k_scan3(int* __restrict__ rp, const int* __restrict__ bsum, int* __restrict__ cursor,
                        const int* __restrict__ dego, const int* __restrict__ degi,
                        float* __restrict__ n_out, float* __restrict__ n_in) {
    int t = threadIdx.x, gid = blockIdx.x * 256 + t;
    int v = rp[gid] + bsum[blockIdx.x];
    rp[gid] = v;
    cursor[gid] = v;
    if (gid == 0) rp[NN] = EE;
    n_out[gid] = rsqrtf((float)max(dego[gid], 1));
    n_in[gid]  = rsqrtf((float)max(degi[gid], 1));
}

__global__ void k_fill(const int* __restrict__ src, const int* __restrict__ dst,
                       int* __restrict__ cursor, int* __restrict__ csr) {
    int e = blockIdx.x * 256 + threadIdx.x;
    int d = dst[e];
    int pos = atomicAdd(&cursor[d], 1);
    csr[pos] = src[e];
}

// per-row conv1 stats: T[r] = n_in[r] * { Σ sc*nf0, Σ sc*nf1, Σ sc },  sc = n_out[src]
__global__ void k_rowstats(const int* __restrict__ rp, const int* __restrict__ csr,
                           const float* __restrict__ n_out, const float* __restrict__ n_in,
                           const float* __restrict__ nf, float* __restrict__ T) {
    int r = blockIdx.x * 256 + threadIdx.x;
    int e0 = rp[r], e1 = rp[r + 1];
    float S0 = 0.f, S1 = 0.f, S2 = 0.f;
    for (int e = e0; e < e1; e++) {
        int s = csr[e];
        float sc = n_out[s];
        S0 = fmaf(sc, nf[2 * s], S0);
        S1 = fmaf(sc, nf[2 * s + 1], S1);
        S2 += sc;
    }
    float ni = n_in[r];
    T[3 * r]     = S0 * ni;
    T[3 * r + 1] = S1 * ni;
    T[3 * r + 2] = S2 * ni;
}

// ---------------- weight / bn prep ----------------
__global__ void k_prep(const float* __restrict__ w0, const float* __restrict__ w1,
                       const float* __restrict__ w2, const float* __restrict__ w3,
                       unsigned short* __restrict__ t0, unsigned short* __restrict__ t1,
                       unsigned short* __restrict__ t2, unsigned short* __restrict__ t3,
                       const float* __restrict__ wcls, unsigned short* __restrict__ tcls,
                       const float* __restrict__ g, const float* __restrict__ b,
                       const float* __restrict__ m, const float* __restrict__ v,
                       float* __restrict__ bns, float* __restrict__ bnh) {
    int t = blockIdx.x * 256 + threadIdx.x;
    int y = blockIdx.y;
    if (y < 4) {
        int k = t >> 8, n = t & 255;
        const float* w = (y == 0) ? w0 : (y == 1) ? w1 : (y == 2) ? w2 : w3;
        unsigned short* o = (y == 0) ? t0 : (y == 1) ? t1 : (y == 2) ? t2 : t3;
        o[n * 256 + k] = f2bf(w[t]);
    } else if (y == 4) {
        if (t < 16384) {
            int n = t >> 8, k = t & 255;
            tcls[t] = (n < 60) ? f2bf(wcls[k * 60 + n]) : (unsigned short)0;
        }
    } else {
        if (t < 1536) {
            float inv = rsqrtf(v[t] + 1e-5f);
            float s = g[t] * inv;
            bns[t] = s;
            bnh[t] = b[t] - m[t] * s;
        }
    }
}

// ---------------- conv1: GEMM1 (A from T,Wemb) -> y -> LDS -> GEMM2 -> H1W; R3 ----------------
// y = emb_resid + relu(bn1(relu(bn0( A @ W1 + b1 ))));  R3 = y @ Wout;
// H1W = (y * n_out[row]) @ W2   (bias b2 / bn2 applied later in k_gconv)
__launch_bounds__(256)
__global__ void k_conv1(const float* __restrict__ T, const float* __restrict__ nf,
                        const float* __restrict__ Wemb, const float* __restrict__ bemb,
                        const unsigned short* __restrict__ Wt1, const float* __restrict__ bias,
                        const unsigned short* __restrict__ Wt2,
                        const float* __restrict__ bns0, const float* __restrict__ bnh0,
                        const float* __restrict__ Wout, const float* __restrict__ n_out,
                        unsigned short* __restrict__ h1w, float* __restrict__ R3) {
    __shared__ unsigned char tileY[64 * 512];   // swizzled bf16 (y * n_out)
    __shared__ float pl[4][64][3];
    int lane = threadIdx.x & 63, wave = threadIdx.x >> 6;
    int wrow = blockIdx.x * 64;
    int rsel = lane & 15, kq = lane >> 4;
    float t0[4], t1[4], t2[4];
#pragma unroll
    for (int mt = 0; mt < 4; mt++) {
        int r = wrow + mt * 16 + rsel;
        t0[mt] = T[3 * r]; t1[mt] = T[3 * r + 1]; t2[mt] = T[3 * r + 2];
    }
    f32x4 acc[4][4];
    f32x4 zero = {0.f, 0.f, 0.f, 0.f};
#pragma unroll
    for (int i = 0; i < 4; i++)
#pragma unroll
        for (int j = 0; j < 4; j++) acc[i][j] = zero;

#pragma unroll
    for (int kt = 0; kt < 8; kt++) {
        int k0 = kt * 32 + kq * 8;
        float w0s[8], w1s[8], bes[8];
        *(float4*)w0s = *(const float4*)(Wemb + k0);       *(float4*)(w0s + 4) = *(const float4*)(Wemb + k0 + 4);
        *(float4*)w1s = *(const float4*)(Wemb + 256 + k0); *(float4*)(w1s + 4) = *(const float4*)(Wemb + 256 + k0 + 4);
        *(float4*)bes = *(const float4*)(bemb + k0);       *(float4*)(bes + 4) = *(const float4*)(bemb + k0 + 4);
        bf16x8 afr[4];
#pragma unroll
        for (int mt = 0; mt < 4; mt++) {
            u16x8 au;
#pragma unroll
            for (int j = 0; j < 8; j++)
                au[j] = f2bf(fmaf(t0[mt], w0s[j], fmaf(t1[mt], w1s[j], t2[mt] * bes[j])));
            afr[mt] = __builtin_bit_cast(bf16x8, au);
        }
        bf16x8 bfr[4];
#pragma unroll
        for (int nt = 0; nt < 4; nt++) {
            u16x8 bu = *(const u16x8*)(Wt1 + (size_t)(wave * 64 + nt * 16 + rsel) * 256 + k0);
            bfr[nt] = __builtin_bit_cast(bf16x8, bu);
        }
#pragma unroll
        for (int mt = 0; mt < 4; mt++)
#pragma unroll
            for (int nt = 0; nt < 4; nt++)
                acc[mt][nt] = __builtin_amdgcn_mfma_f32_16x16x32_bf16(afr[mt], bfr[nt], acc[mt][nt], 0, 0, 0);
    }

    // epilogue A: bn chain + emb residual; y*n_out -> LDS tile; pose partials -> pl
#pragma unroll
    for (int mt = 0; mt < 4; mt++) {
        float f0[4], f1[4], no[4];
        float p0[4] = {0.f, 0.f, 0.f, 0.f};
        float p1[4] = {0.f, 0.f, 0.f, 0.f};
        float p2[4] = {0.f, 0.f, 0.f, 0.f};
#pragma unroll
        for (int r = 0; r < 4; r++) {
            int row = wrow + mt * 16 + kq * 4 + r;
            float2 p = *(const float2*)(nf + 2 * (size_t)row);
            f0[r] = p.x; f1[r] = p.y;
            no[r] = n_out[row];
        }
#pragma unroll
        for (int nt = 0; nt < 4; nt++) {
            int col = wave * 64 + nt * 16 + rsel;
            float bc = bias[col];
            float s0 = bns0[col], h0 = bnh0[col];
            float s1 = bns0[256 + col], h1v = bnh0[256 + col];
            float we0 = Wemb[col], we1 = Wemb[256 + col], be = bemb[col];
            const float* wp = Wout + (size_t)col * 3;
            float w30 = wp[0], w31 = wp[1], w32 = wp[2];
#pragma unroll
            for (int r = 0; r < 4; r++) {
                int lrow = mt * 16 + kq * 4 + r;
                float y = acc[mt][nt][r] + bc;
                y = fmaxf(fmaf(y, s0, h0), 0.f);
                y = fmaxf(fmaf(y, s1, h1v), 0.f);
                y += fmaf(f0[r], we0, fmaf(f1[r], we1, be));
                *(unsigned short*)(tileY + lrow * 512 + ((col * 2) ^ ((lrow & 7) << 4))) = f2bf(y * no[r]);
                p0[r] = fmaf(y, w30, p0[r]);
                p1[r] = fmaf(y, w31, p1[r]);
                p2[r] = fmaf(y, w32, p2[r]);
            }
        }
#pragma unroll
        for (int m = 1; m < 16; m <<= 1) {
#pragma unroll
            for (int r = 0; r < 4; r++) {
                p0[r] += __shfl_xor(p0[r], m);
                p1[r] += __shfl_xor(p1[r], m);
                p2[r] += __shfl_xor(p2[r], m);
            }
        }
        if (rsel == 0) {
#pragma unroll
            for (int r = 0; r < 4; r++) {
                int lrow = mt * 16 + kq * 4 + r;
                pl[wave][lrow][0] = p0[r];
                pl[wave][lrow][1] = p1[r];
                pl[wave][lrow][2] = p2[r];
            }
        }
    }
    __syncthreads();
    int tid = threadIdx.x;
    if (tid < 192) {
        int lrow = tid / 3, c = tid % 3;
        R3[(size_t)(wrow + lrow) * 3 + c] =
            pl[0][lrow][c] + pl[1][lrow][c] + pl[2][lrow][c] + pl[3][lrow][c];
    }

    // phase B: H1W = tileY @ W2
    f32x4 acc2[4][4];
#pragma unroll
    for (int i = 0; i < 4; i++)
#pragma unroll
        for (int j = 0; j < 4; j++) acc2[i][j] = zero;
#pragma unroll
    for (int kt = 0; kt < 8; kt++) {
        int cb = kt * 64 + kq * 16;
        int k0 = kt * 32 + kq * 8;
        bf16x8 afr[4];
#pragma unroll
        for (int mt = 0; mt < 4; mt++) {
            int ar = mt * 16 + rsel;
            u16x8 au = *(const u16x8*)(tileY + ar * 512 + (cb ^ ((ar & 7) << 4)));
            afr[mt] = __builtin_bit_cast(bf16x8, au);
        }
        bf16x8 bfr[4];
#pragma unroll
        for (int nt = 0; nt < 4; nt++) {
            u16x8 bu = *(const u16x8*)(Wt2 + (size_t)(wave * 64 + nt * 16 + rsel) * 256 + k0);
            bfr[nt] = __builtin_bit_cast(bf16x8, bu);
        }
#pragma unroll
        for (int mt = 0; mt < 4; mt++)
#pragma unroll
            for (int nt = 0; nt < 4; nt++)
                acc2[mt][nt] = __builtin_amdgcn_mfma_f32_16x16x32_bf16(afr[mt], bfr[nt], acc2[mt][nt], 0, 0, 0);
    }
#pragma unroll
    for (int mt = 0; mt < 4; mt++)
#pragma unroll
        for (int nt = 0; nt < 4; nt++) {
            int col = wave * 64 + nt * 16 + rsel;
#pragma unroll
            for (int r = 0; r < 4; r++) {
                int row = wrow + mt * 16 + kq * 4 + r;
                h1w[(size_t)row * 256 + col] = f2bf(acc2[mt][nt][r]);
            }
        }
}

// ---------------- k_gconv: gather H1W rows + bn/relu + pose dot (no GEMM/atomics/LDS) ----
// One row per half-wave, 8 rows each. a = Σ_src H1W[src] (fp32 regs);
// y = relu(bn3(relu(bn2(a*n_in + b2))));  h3d = y@Wout + R3 + bout (shfl reduce).
__launch_bounds__(256)
__global__ void k_gconv(const int* __restrict__ rp, const int* __restrict__ csr,
                        const float* __restrict__ n_in, const unsigned short* __restrict__ h1w,
                        const float* __restrict__ bc2,
                        const float* __restrict__ bns0, const float* __restrict__ bnh0,
                        const float* __restrict__ Wout, const float* __restrict__ bout,
                        const float* __restrict__ R3, float* __restrict__ h3d) {
    int hw = threadIdx.x >> 5;        // 0..7 half-waves
    int l = threadIdx.x & 31;
    int c0 = l * 8;                   // 8 channels per lane

    // per-lane channel params (reused across 8 rows)
    float bc[8], s0[8], h0[8], s1[8], h1v[8], w0[8], w1[8], w2[8];
#pragma unroll
    for (int j = 0; j < 8; j += 4) {
        *(float4*)(bc + j)  = *(const float4*)(bc2 + c0 + j);
        *(float4*)(s0 + j)  = *(const float4*)(bns0 + c0 + j);
        *(float4*)(h0 + j)  = *(const float4*)(bnh0 + c0 + j);
        *(float4*)(s1 + j)  = *(const float4*)(bns0 + 256 + c0 + j);
        *(float4*)(h1v + j) = *(const float4*)(bnh0 + 256 + c0 + j);
    }
#pragma unroll
    for (int j = 0; j < 8; j++) {
        const float* wp = Wout + (size_t)(c0 + j) * 3;
        w0[j] = wp[0]; w1[j] = wp[1]; w2[j] = wp[2];
    }
    float b0 = bout[0], b1 = bout[1], b2v = bout[2];

    int rbase = blockIdx.x * 64 + hw * 8;
#pragma unroll 1
    for (int i = 0; i < 8; i++) {
        int row = rbase + i;
        int e0 = rp[row], e1 = rp[row + 1];
        float a[8] = {0.f, 0.f, 0.f, 0.f, 0.f, 0.f, 0.f, 0.f};
        for (int e = e0; e < e1; e++) {
            int s = csr[e];
            u16x8 v = *(const u16x8*)(h1w + ((size_t)s << 8) + c0);
#pragma unroll
            for (int j = 0; j < 8; j++) a[j] += bf2f(v[j]);
        }
        float ni = n_in[row];
        float p0 = 0.f, p1 = 0.f, p2 = 0.f;
#pragma unroll
        for (int j = 0; j < 8; j++) {
            float y = fmaf(a[j], ni, bc[j]);
            y = fmaxf(fmaf(y, s0[j], h0[j]), 0.f);
            y = fmaxf(fmaf(y, s1[j], h1v[j]), 0.f);
            p0 = fmaf(y, w0[j], p0);
            p1 = fmaf(y, w1[j], p1);
            p2 = fmaf(y, w2[j], p2);
        }
#pragma unroll
        for (int m = 1; m < 32; m <<= 1) {
            p0 += __shfl_xor(p0, m, 32);
            p1 += __shfl_xor(p1, m, 32);
            p2 += __shfl_xor(p2, m, 32);
        }
        if (l == 0) {
            size_t o = (size_t)row * 3;
            h3d[o]     = p0 + R3[o]     + b0;
            h3d[o + 1] = p1 + R3[o + 1] + b1;
            h3d[o + 2] = p2 + R3[o + 2] + b2v;
        }
    }
}

// ---------------- fused classification head (gmean via binary search) ----------------
__launch_bounds__(256)
__global__ void k_head(const int* __restrict__ n2g, const float* __restrict__ h3d,
                       const float* __restrict__ Wci, const float* __restrict__ bci,
                       const unsigned short* __restrict__ wta, const float* __restrict__ ba,
                       const unsigned short* __restrict__ wtb, const float* __restrict__ bb,
                       const unsigned short* __restrict__ wtcls, const float* __restrict__ bcls,
                       const float* __restrict__ bns, const float* __restrict__ bnh,
                       float* __restrict__ label) {
    __shared__ unsigned char smem[65536];
    int lane = threadIdx.x & 63, wave = threadIdx.x >> 6;
    unsigned char* tileA = smem + wave * 8192;
    unsigned char* tileB = smem + 32768 + wave * 8192;
    int wrow = blockIdx.x * 64 + wave * 16;
    int rsel = lane & 15, kq = lane >> 4;
    int g = wrow + rsel;              // graph id for this lane

    // graph node range via binary search on sorted n2g
    int lo = 0, hi = NN;
    while (lo < hi) { int mid = (lo + hi) >> 1; if (n2g[mid] < g) lo = mid + 1; else hi = mid; }
    int s = lo;
    hi = NN;
    while (lo < hi) { int mid = (lo + hi) >> 1; if (n2g[mid] < g + 1) lo = mid + 1; else hi = mid; }
    int e = lo;
    float m0 = 0.f, m1 = 0.f, m2 = 0.f;
    for (int j = s; j < e; j++) {
        m0 += h3d[(size_t)j * 3];
        m1 += h3d[(size_t)j * 3 + 1];
        m2 += h3d[(size_t)j * 3 + 2];
    }
    float inv = 1.f / fmaxf((float)(e - s), 1.f);
    m0 *= inv; m1 *= inv; m2 *= inv;

    f32x4 zero = {0.f, 0.f, 0.f, 0.f};
    f32x4 acc[16];
#pragma unroll
    for (int i = 0; i < 16; i++) acc[i] = zero;

    // stage 1: z1 = relu(bn4(z0 @ Wa + ba)), z0 built on the fly
#pragma unroll
    for (int kt = 0; kt < 8; kt++) {
        int k0 = kt * 32 + kq * 8;
        u16x8 au;
#pragma unroll
        for (int j = 0; j < 8; j++)
            au[j] = f2bf(fmaf(m0, Wci[k0 + j], fmaf(m1, Wci[256 + k0 + j],
                         fmaf(m2, Wci[512 + k0 + j], bci[k0 + j]))));
        bf16x8 af = __builtin_bit_cast(bf16x8, au);
#pragma unroll
        for (int nt = 0; nt < 16; nt++) {
            u16x8 bu = *(const u16x8*)(wta + (size_t)(nt * 16 + rsel) * 256 + k0);
            acc[nt] = __builtin_amdgcn_mfma_f32_16x16x32_bf16(af, __builtin_bit_cast(bf16x8, bu), acc[nt], 0, 0, 0);
        }
    }
#pragma unroll
    for (int nt = 0; nt < 16; nt++) {
        int col = nt * 16 + rsel;
        float bcv = ba[col];
        float sc = bns[4 * 256 + col], h = bnh[4 * 256 + col];
#pragma unroll
        for (int r = 0; r < 4; r++) {
            float y = fmaxf(fmaf(acc[nt][r] + bcv, sc, h), 0.f);
            int rr = kq * 4 + r;
            *(unsigned short*)(tileA + rr * 512 + ((col * 2) ^ ((rr & 7) << 4))) = f2bf(y);
        }
    }

    // stage 2: z2 = relu(bn5(z1 @ Wb + bb))
#pragma unroll
    for (int i = 0; i < 16; i++) acc[i] = zero;
#pragma unroll
    for (int kt = 0; kt < 8; kt++) {
        int cb = kt * 64 + kq * 16;
        u16x8 au = *(const u16x8*)(tileA + rsel * 512 + (cb ^ ((rsel & 7) << 4)));
        bf16x8 af = __builtin_bit_cast(bf16x8, au);
        int k0 = kt * 32 + kq * 8;
#pragma unroll
        for (int nt = 0; nt < 16; nt++) {
            u16x8 bu = *(const u16x8*)(wtb + (size_t)(nt * 16 + rsel) * 256 + k0);
            acc[nt] = __builtin_amdgcn_mfma_f32_16x16x32_bf16(af, __builtin_bit_cast(bf16x8, bu), acc[nt], 0, 0, 0);
        }
    }
#pragma unroll
    for (int nt = 0; nt < 16; nt++) {
        int col = nt * 16 + rsel;
        float bcv = bb[col];
        float sc = bns[5 * 256 + col], h = bnh[5 * 256 + col];
#pragma unroll
        for (int r = 0; r < 4; r++) {
            float y = fmaxf(fmaf(acc[nt][r] + bcv, sc, h), 0.f);
            int rr = kq * 4 + r;
            *(unsigned short*)(tileB + rr * 512 + ((col * 2) ^ ((rr & 7) << 4))) = f2bf(y);
        }
    }

    // stage 3: label = z2 @ Wcls + bcls (60 cols)
    f32x4 acc3[4];
#pragma unroll
    for (int i = 0; i < 4; i++) acc3[i] = zero;
#pragma unroll
    for (int kt = 0; kt < 8; kt++) {
        int cb = kt * 64 + kq * 16;
        u16x8 au = *(const u16x8*)(tileB + rsel * 512 + (cb ^ ((rsel & 7) << 4)));
        bf16x8 af = __builtin_bit_cast(bf16x8, au);
        int k0 = kt * 32 + kq * 8;
#pragma unroll
        for (int nt = 0; nt < 4; nt++) {
            u16x8 bu = *(const u16x8*)(wtcls + (size_t)(nt * 16 + rsel) * 256 + k0);
            acc3[nt] = __builtin_amdgcn_mfma_f32_16x16x32_bf16(af, __builtin_bit_cast(bf16x8, bu), acc3[nt], 0, 0, 0);
        }
    }
    int rowb = wrow + kq * 4;
#pragma unroll
    for (int nt = 0; nt < 4; nt++) {
        int col = nt * 16 + rsel;
        if (col < 60) {
            float bcv = bcls[col];
#pragma unroll
            for (int r = 0; r < 4; r++)
                label[(size_t)(rowb + r) * 60 + col] = acc3[nt][r] + bcv;
        }
    }
}

// ---------------- launch ----------------
extern "C" void kernel_launch(void* const* d_in, const int* in_sizes, int n_in,
                              void* d_out, int out_size, void* d_ws, size_t ws_size,
                              hipStream_t stream) {
    const float* nf   = (const float*)d_in[0];
    const int* src    = (const int*)d_in[1];
    const int* dst    = (const int*)d_in[2];
    const int* n2g    = (const int*)d_in[3];
    const float* Wemb = (const float*)d_in[4];
    const float* bemb = (const float*)d_in[5];
    const float* Wc1  = (const float*)d_in[6];
    const float* bc1  = (const float*)d_in[7];
    const float* Wc2  = (const float*)d_in[8];
    const float* bc2  = (const float*)d_in[9];
    const float* bng  = (const float*)d_in[10];
    const float* bnb  = (const float*)d_in[11];
    const float* bnm  = (const float*)d_in[12];
    const float* bnv  = (const float*)d_in[13];
    const float* Wout = (const float*)d_in[14];
    const float* bout = (const float*)d_in[15];
    const float* Wci  = (const float*)d_in[16];
    const float* bci  = (const float*)d_in[17];
    const float* Wb3a = (const float*)d_in[18];
    const float* bb3a = (const float*)d_in[19];
    const float* Wb3b = (const float*)d_in[20];
    const float* bb3b = (const float*)d_in[21];
    const float* Wcls = (const float*)d_in[22];
    const float* bcls = (const float*)d_in[23];

    char* ws = (char*)d_ws;
    int* deg_out = (int*)(ws + OFF_DEG_OUT);
    int* deg_in  = (int*)(ws + OFF_DEG_IN);
    float* n_out = (float*)(ws + OFF_NOUT);
    float* n_inp = (float*)(ws + OFF_NIN);
    int* row_ptr = (int*)(ws + OFF_ROWPTR);
    int* cursor  = (int*)(ws + OFF_CURSOR);
    int* csr_src = (int*)(ws + OFF_CSRS);
    int* bsum    = (int*)(ws + OFF_BSUM);
    unsigned short* wt1   = (unsigned short*)(ws + OFF_WT1);
    unsigned short* wt2   = (unsigned short*)(ws + OFF_WT2);
    unsigned short* wta   = (unsigned short*)(ws + OFF_WTA);
    unsigned short* wtb   = (unsigned short*)(ws + OFF_WTB);
    unsigned short* wtcls = (unsigned short*)(ws + OFF_WTCLS);
    float* bns = (float*)(ws + OFF_BNS);
    float* bnh = (float*)(ws + OFF_BNH);
    float* T   = (float*)(ws + OFF_T);
    float* R3  = (float*)(ws + OFF_R3);
    unsigned short* h1w = (unsigned short*)(ws + OFF_H1W);

    float* h3d_out   = (float*)d_out;
    float* label_out = (float*)d_out + (size_t)NN * 3;

    hipMemsetAsync(ws, 0, ZERO_BYTES, stream);   // deg_out, deg_in

    k_deg<<<EBLK, 256, 0, stream>>>(src, dst, deg_out, deg_in);
    k_scan1<<<NBLK, 256, 0, stream>>>(deg_in, row_ptr, bsum);
    k_scan2<<<1, 1024, 0, stream>>>(bsum);
    k_scan3<<<NBLK, 256, 0, stream>>>(row_ptr, bsum, cursor, deg_out, deg_in, n_out, n_inp);
    k_fill<<<EBLK, 256, 0, stream>>>(src, dst, cursor, csr_src);
    k_prep<<<dim3(256, 6), 256, 0, stream>>>(Wc1, Wc2, Wb3a, Wb3b, wt1, wt2, wta, wtb,
                                             Wcls, wtcls, bng, bnb, bnm, bnv, bns, bnh);
    k_rowstats<<<NBLK, 256, 0, stream>>>(row_ptr, csr_src, n_out, n_inp, nf, T);

    k_conv1<<<NN / 64, 256, 0, stream>>>(T, nf, Wemb, bemb, wt1, bc1, wt2,
                                         bns, bnh, Wout, n_out, h1w, R3);
    k_gconv<<<NN / 64, 256, 0, stream>>>(row_ptr, csr_src, n_inp, h1w, bc2,
                                         bns + 512, bnh + 512, Wout, bout, R3, h3d_out);
    k_head<<<GG / 64, 256, 0, stream>>>(n2g, h3d_out, Wci, bci, wta, bb3a, wtb, bb3b,
                                        wtcls, bcls, bns, bnh, label_out);
}